// Round 9
// baseline (365.037 us; speedup 1.0000x reference)
//
#include <hip/hip_runtime.h>
#include <math.h>

// N=64, C=256, T=64, V=25 graph-ODE, 4 fused blocks. bf16 MFMA 32x32x16.
// R7: best scheduled 2-phase structure: 181.5us (syT LDS round-trip, 9 barriers).
// R8-R10: occupancy invariant ~42% -> register-file capped. Occupancy lever dead.
// R11/R12: ALGEBRAIC RESTRUCTURE out = A·(w·res): big GEMM z[u,o] first
//     (A-op = transposed residual sresT, contiguous conflict-free b128;
//     B-op = packed w), then tiny A-mix on z in-register via the R8-verified
//     pack+permlane32_swap D->B-frag transform. syT eliminated; sresT
//     double-buffered; ONE barrier per block (5 total vs R7's 9).
//     R12 FAILED (absmax 15.9): convert_w loaded w TRANSPOSED.
// R13: fix = revert convert_w to the R0-R7 pack verbatim. The same layout
//     serves as A-frag (w as A-operand, old) and B-frag (w as B-operand,
//     new): B[kk][n] = value(lane n, elem kk) = w[o=n][c=kk]. Verified by
//     unit-trace w=e_{0,1}. ode_mfma unchanged from R11.
#define NN 64
#define CC 256
#define TT 64
#define VV 25

typedef __bf16 bf16;
typedef __attribute__((ext_vector_type(8)))  __bf16 bf16x8;
typedef __attribute__((ext_vector_type(16))) float  f32x16;
typedef __attribute__((ext_vector_type(4)))  unsigned int uint4v;

#define RST 266   // sresT row stride (bf16): 532 B = 133 dwords -> bank stride 5,
                  // gcd(5,32)=1 -> 32 lanes hit 32 distinct banks on b128 reads.

// Manual LDS layout (bytes).
#define OFF_S0    0        // 32*266*2 = 17024
#define OFF_S1    17024    // 17024
#define OFF_SAB   34048    // 32*32*2  = 2048
#define OFF_SBIAS 36096    // 4*256*4  = 4096
#define SMEM_BYTES 40192   // <= 40960 -> 4 WGs/CU

// ---- pack the four 256x256 fp32 w into bf16 MFMA fragment order (R0-R7
//      verbatim). wp[((blk*4+wv)*16+k)*1024 + pair*512 + lane*8 + e]
//        = w_blk[wv*64+pair*32+(lane&31)][k*16+(lane>>5)*8+e]
//      Used as B-operand: B[kk][n] = value(lane=n, elem=kk) = w[o=n][c=kk],
//      giving z[u][o] = sum_c resT[u][c]*w[o][c]. ----
__global__ void convert_w(const float* __restrict__ w1, const float* __restrict__ w2,
                          const float* __restrict__ w3, const float* __restrict__ w4,
                          bf16* __restrict__ wp) {
    const int gid = blockIdx.x * 256 + threadIdx.x;   // 0..32767
    const int e8  = gid * 8;                          // linear over 4*65536 elems
    const int blk = e8 >> 16;
    const int off = e8 & 65535;
    const int row = off >> 8;
    const int col = off & 255;
    const float* src = (blk == 0) ? w1 : (blk == 1) ? w2 : (blk == 2) ? w3 : w4;
    const float4 f0 = *(const float4*)(src + off);        // coalesced reads
    const float4 f1 = *(const float4*)(src + off + 4);
    bf16x8 o;
    o[0] = (bf16)f0.x; o[1] = (bf16)f0.y; o[2] = (bf16)f0.z; o[3] = (bf16)f0.w;
    o[4] = (bf16)f1.x; o[5] = (bf16)f1.y; o[6] = (bf16)f1.z; o[7] = (bf16)f1.w;
    const int wv = row >> 6, pair = (row >> 5) & 1, l31 = row & 31;
    const int k = col >> 4, lh = (col >> 3) & 1;
    wp += (((size_t)(blk * 4 + wv) * 16 + k) * 1024) + pair * 512 + (lh * 32 + l31) * 8;
    *(bf16x8*)wp = o;
}

#define MFMA(A, B, C) __builtin_amdgcn_mfma_f32_32x32x16_bf16(A, B, C, 0, 0, 0)

// pack two f32 -> one dword of 2 bf16 (lo, hi)
static __device__ __forceinline__ unsigned int pkbf(float a, float b) {
    unsigned short lo = __builtin_bit_cast(unsigned short, (__bf16)a);
    unsigned short hi = __builtin_bit_cast(unsigned short, (__bf16)b);
    return (unsigned int)lo | ((unsigned int)hi << 16);
}

__global__ __launch_bounds__(256, 4) void ode_mfma(
    const float* __restrict__ x, const float* __restrict__ Amat,
    const bf16* __restrict__ wp,
    const float* __restrict__ b1, const float* __restrict__ b2,
    const float* __restrict__ b3, const float* __restrict__ b4,
    float* __restrict__ out)
{
    __shared__ __attribute__((aligned(16))) char smem[SMEM_BYTES];
    bf16*  s0    = (bf16*)(smem + OFF_S0);      // res^T buf0: [u(32)][RST]
    bf16*  s1    = (bf16*)(smem + OFF_S1);      // res^T buf1
    bf16*  sAb   = (bf16*)(smem + OFF_SAB);     // A zero-padded [v(32)][32]
    float* sbias = (float*)(smem + OFF_SBIAS);  // [4][CC]

    const int t    = blockIdx.x;
    const int n    = blockIdx.y;
    const int tid  = threadIdx.x;
    const int wave = tid >> 6;
    const int lane = tid & 63;
    const int lh   = lane >> 5;
    const int l31  = lane & 31;
    const int o0   = wave * 64;

    // ---- blk0 w-prefetch: no LDS dependency; hides under staging ----
    bf16x8 wA[4], wB[4];   // wA = pair0 (o-cols +0..31), wB = pair1 (+32..63)
    {
        const bf16* wb0 = wp + ((size_t)wave * 16) * 1024 + lane * 8;
        #pragma unroll
        for (int q = 0; q < 4; ++q) {
            wA[q] = *(const bf16x8*)(wb0 + q * 1024);
            wB[q] = *(const bf16x8*)(wb0 + q * 1024 + 512);
        }
    }

    // ---- stage biases (coalesced) ----
    sbias[0 * CC + tid] = b1[tid];
    sbias[1 * CC + tid] = b2[tid];
    sbias[2 * CC + tid] = b3[tid];
    sbias[3 * CC + tid] = b4[tid];

    // ---- stage A, zero-padded to 32x32 (consumed as A-fragments: rows v) ----
    for (int i = tid; i < 32 * 32; i += 256) {
        const int v = i >> 5, u = i & 31;
        sAb[i] = (v < VV && u < VV) ? (bf16)Amat[v * VV + u] : (bf16)0.f;
    }

    // ---- zero rows u=25..31 of BOTH buffers (never rewritten; keeps the big
    //      GEMM's padded rows exactly 0 -> no NaN/garbage can propagate) ----
    for (int i = tid; i < 7 * 256; i += 256) {
        const int r = 25 + (i >> 8), c = i & 255;
        s0[r * RST + c] = (bf16)0.f;
        s1[r * RST + c] = (bf16)0.f;
    }

    // ---- stage x slab TRANSPOSED: s0[v][c] = x[n,c,t,v] ----
    {
        const float* xb = x + ((size_t)n * CC * TT + t) * VV;
        for (int i = tid; i < CC * VV; i += 256) {
            const int c = i / VV;
            const int v = i - c * VV;
            s0[v * RST + c] = (bf16)xb[(size_t)c * TT * VV + v];
        }
    }
    __syncthreads();

    // Amat A-fragments (rows v = l31, cols u = ks*16 + lh*8 + e), both k-steps.
    const bf16x8 bfA0 = *(const bf16x8*)&sAb[l31 * 32 + lh * 8];
    const bf16x8 bfA1 = *(const bf16x8*)&sAb[l31 * 32 + 16 + lh * 8];

    for (int blk = 0; blk < 4; ++blk) {
        bf16* rd = (blk & 1) ? s1 : s0;
        bf16* wr = (blk & 1) ? s0 : s1;
        const bf16* wbase = wp + ((size_t)(blk * 4 + wave) * 16) * 1024 + lane * 8;

        // ===== big GEMM: z[u,o] = sum_c resT[u,c] * w[o,c], K=256 =====
        // A-op: sresT row u=l31 (1x ds_read_b128/k-step, conflict-free);
        // B-op: packed w fragments, rotated depth-4 prefetch.
        f32x16 z0 = {}, z1 = {};
        bf16x8 af[2];
        af[0] = *(const bf16x8*)&rd[l31 * RST + lh * 8];
        #pragma unroll
        for (int k = 0; k < 16; ++k) {
            if (k < 15)
                af[(k + 1) & 1] = *(const bf16x8*)&rd[l31 * RST + (k + 1) * 16 + lh * 8];
            const bf16x8 a = af[k & 1];
            z0 = MFMA(a, wA[k & 3], z0);
            z1 = MFMA(a, wB[k & 3], z1);
            if (k + 4 < 16) {
                wA[k & 3] = *(const bf16x8*)(wbase + (k + 4) * 1024);
                wB[k & 3] = *(const bf16x8*)(wbase + (k + 4) * 1024 + 512);
            }
        }

        // ---- prefetch next block's w: hides under pack+mix+epilogue ----
        if (blk < 3) {
            const bf16* wn = wp + ((size_t)((blk + 1) * 4 + wave) * 16) * 1024 + lane * 8;
            #pragma unroll
            for (int q = 0; q < 4; ++q) {
                wA[q] = *(const bf16x8*)(wn + q * 1024);
                wB[q] = *(const bf16x8*)(wn + q * 1024 + 512);
            }
        }

        // ===== per o-tile: z (D-layout) -> B-frags (R8-verified transform),
        //       tiny A-mix (2 MFMAs), epilogue =====
        #define FINAL_TILE(ZZ, TL)                                                  \
        {                                                                           \
            unsigned int a0 = pkbf(ZZ[0],  ZZ[1]),  a1 = pkbf(ZZ[2],  ZZ[3]);       \
            unsigned int a2 = pkbf(ZZ[4],  ZZ[5]),  a3 = pkbf(ZZ[6],  ZZ[7]);       \
            unsigned int a4 = pkbf(ZZ[8],  ZZ[9]),  a5 = pkbf(ZZ[10], ZZ[11]);      \
            unsigned int a6 = pkbf(ZZ[12], ZZ[13]), a7 = pkbf(ZZ[14], ZZ[15]);      \
            asm("v_permlane32_swap_b32 %0, %1" : "+v"(a0), "+v"(a2));               \
            asm("v_permlane32_swap_b32 %0, %1" : "+v"(a1), "+v"(a3));               \
            asm("v_permlane32_swap_b32 %0, %1" : "+v"(a4), "+v"(a6));               \
            asm("v_permlane32_swap_b32 %0, %1" : "+v"(a5), "+v"(a7));               \
            const bf16x8 y0 = __builtin_bit_cast(bf16x8, (uint4v){a0, a1, a2, a3}); \
            const bf16x8 y1 = __builtin_bit_cast(bf16x8, (uint4v){a4, a5, a6, a7}); \
            f32x16 d = {};                                                          \
            d = MFMA(bfA0, y0, d);                                                  \
            d = MFMA(bfA1, y1, d);                                                  \
            const int o = o0 + (TL) * 32 + l31;                                     \
            const float bb = sbias[blk * CC + o];                                   \
            _Pragma("unroll")                                                       \
            for (int q = 0; q < 16; ++q) {                                          \
                const int v = (q & 3) + 8 * (q >> 2) + 4 * lh;                      \
                float val = d[q] + bb + (float)rd[v * RST + o];                     \
                val = fmaxf(val, 0.f);                                              \
                if (v < VV) {                                                       \
                    if (blk < 3) wr[v * RST + o] = (bf16)val;                       \
                    else out[(((size_t)n * CC + o) * TT + t) * VV + v] = val;       \
                }                                                                   \
            }                                                                       \
        }
        FINAL_TILE(z0, 0)
        FINAL_TILE(z1, 1)
        #undef FINAL_TILE

        // ONE barrier per block: k-loop reads rd only, epilogue writes wr only
        // -> the only hazard is wr-writes vs next block's rd-reads.
        if (blk < 3) __syncthreads();
    }
}

extern "C" void kernel_launch(void* const* d_in, const int* in_sizes, int n_in,
                              void* d_out, int out_size, void* d_ws, size_t ws_size,
                              hipStream_t stream) {
    const float* x  = (const float*)d_in[1];
    const float* A  = (const float*)d_in[2];
    const float* w1 = (const float*)d_in[3];
    const float* b1 = (const float*)d_in[4];
    const float* w2 = (const float*)d_in[5];
    const float* b2 = (const float*)d_in[6];
    const float* w3 = (const float*)d_in[7];
    const float* b3 = (const float*)d_in[8];
    const float* w4 = (const float*)d_in[9];
    const float* b4 = (const float*)d_in[10];
    float* out = (float*)d_out;
    bf16* wp = (bf16*)d_ws;   // 512 KB packed w fragments

    convert_w<<<128, 256, 0, stream>>>(w1, w2, w3, w4, wp);
    dim3 grid(TT, NN);        // one WG per (n,t) slab: 4096 WGs
    ode_mfma<<<grid, 256, 0, stream>>>(x, A, wp, b1, b2, b3, b4, out);
}